// Round 13
// baseline (176.875 us; speedup 1.0000x reference)
//
#include <hip/hip_runtime.h>

// DCNv2 fused v15 = v14 + (1) 4-bit XOR weight swizzle (was 3-bit): each
// 16-lane group now spans all 16 slots/256B of a row -> 2-way bank alias
// only (free, m136); old 3-bit form put all 64 lanes on 8 slots/128B ->
// +4cy/read measured (5.3M conflict cyc). Read slot = (cb*4+quad)^l15 is
// ot-invariant -> 8 ot reads = base + immediate offsets. Both sides
// changed together (pack + read). (2) packed bilinear: v_pk_fma_f32 /
// v_pk_mul_f32 on {lo,hi} channel pairs, ~-23% bilinear VALU.
// v14 diagnosis: TLP exhausted (4 blocks/CU, dur flat); largest remaining
// line items are LDS-read pipe (incl 4cy/read conflicts) and VALU.

#define NI 8
#define CI 128
#define HI 96
#define WI 96
#define CO 128
#define K2 9
#define P_TOT 9216
#define TP 64
#define NTILE 144                                   // 24 ty * 6 tx
#define CPAD 40
#define XT_ELEMS ((size_t)NI * P_TOT * CI)          // 9,437,184 bf16
#define WT_ELEMS ((size_t)K2 * CO * CI)             // 147,456 bf16
#define WS_NEED ((XT_ELEMS + WT_ELEMS) * 2)
#define PLANE ((size_t)P_TOT * 8)                   // ushorts per chunk-plane

typedef short short8 __attribute__((ext_vector_type(8)));
typedef float f32x4 __attribute__((ext_vector_type(4)));

static __device__ __forceinline__ ushort bf16_rne(float x) {
    unsigned u = __float_as_uint(x);
    u = (u + 0x7FFF + ((u >> 16) & 1)) >> 16;
    return (ushort)u;
}
static __device__ __forceinline__ unsigned pack_bf2(float a, float b) {
    return (unsigned)bf16_rne(a) | ((unsigned)bf16_rne(b) << 16);
}
static __device__ __forceinline__ unsigned cvt_pk_bf16(float a, float b) {
    unsigned r;
    asm("v_cvt_pk_bf16_f32 %0, %1, %2" : "=v"(r) : "v"(a), "v"(b));
    return r;
}
static __device__ __forceinline__ float bflo(unsigned u) { return __uint_as_float(u << 16); }
static __device__ __forceinline__ float bfhi(unsigned u) { return __uint_as_float(u & 0xFFFF0000u); }
// bf16 pair -> f32 pair
static __device__ __forceinline__ float2 unpk(unsigned u) {
    return make_float2(bflo(u), bfhi(u));
}
// packed 2xf32 ops (VOP3P)
static __device__ __forceinline__ float2 pk_mul(float2 a, float2 b) {
    float2 d;
    asm("v_pk_mul_f32 %0, %1, %2" : "=v"(d) : "v"(a), "v"(b));
    return d;
}
static __device__ __forceinline__ float2 pk_fma(float2 a, float2 b, float2 c) {
    float2 d;
    asm("v_pk_fma_f32 %0, %1, %2, %3" : "=v"(d) : "v"(a), "v"(b), "v"(c));
    return d;
}

union U4S8 { uint4 u; short8 s; };

// async global->LDS, 16B per lane; LDS dest = wave-uniform base + lane*16
static __device__ __forceinline__ void gll16(const ushort* g, ushort* l) {
    __builtin_amdgcn_global_load_lds(
        (const __attribute__((address_space(1))) unsigned int*)g,
        (__attribute__((address_space(3))) unsigned int*)l, 16, 0, 0);
}

// ---- pre-kernel: grid = 2304 (x transpose) + 72 (weight recast+swizzle) ----
__global__ __launch_bounds__(256)
void pre_kernel(const float* __restrict__ x, const float* __restrict__ w,
                ushort* __restrict__ xt, ushort* __restrict__ wt) {
    const int bid = blockIdx.x;
    const int tid = threadIdx.x;
    if (bid < 2304) {
        // transpose x[n][c][hw] fp32 -> xt[n][chunk(16)][hw][8ch] bf16
        __shared__ ushort t[64][68];
        const int n = bid / 288, rr = bid % 288;
        const int cblk = rr & 1, hw0 = (rr >> 1) * 64;
        #pragma unroll
        for (int j = 0; j < 4; ++j) {
            int item = j * 256 + tid;               // < 1024
            int c = item >> 4, q = item & 15;
            float4 f = *(const float4*)(x + ((size_t)(n * CI + cblk * 64 + c)) * P_TOT
                                        + hw0 + q * 4);
            t[q * 4 + 0][c] = bf16_rne(f.x);
            t[q * 4 + 1][c] = bf16_rne(f.y);
            t[q * 4 + 2][c] = bf16_rne(f.z);
            t[q * 4 + 3][c] = bf16_rne(f.w);
        }
        __syncthreads();
        #pragma unroll
        for (int j = 0; j < 4; ++j) {
            int item = j * 256 + tid;               // < 1024
            int row = item >> 4, seg = item & 15;   // seg = 4-ch group
            uint2 v = *(const uint2*)&t[row][seg * 4];
            int chunk = cblk * 8 + (seg >> 1);      // 8-ch plane index
            int sub   = (seg & 1) * 4;
            *(uint2*)(xt + ((size_t)n * 16 + chunk) * PLANE
                         + (size_t)(hw0 + row) * 8 + sub) = v;
        }
    } else {
        // wt swizzled for LDS (4-bit XOR): slot s = k*2048 + o*16 + csw
        // holds 8 ch of c-seg cs = csw ^ (o&15); DMA's linear fill gives
        // the swizzled layout. Read side: slot = cs ^ (o&15).
        int s = (bid - 2304) * 256 + tid;           // < 18432
        int k   = s >> 11;
        int r2  = s & 2047;
        int o   = r2 >> 4;
        int csw = r2 & 15;
        int cs  = csw ^ (o & 15);
        const float* src = w + (size_t)o * (CI * K2) + cs * 8 * K2 + k;
        ushort tmp[8];
        #pragma unroll
        for (int j = 0; j < 8; ++j) tmp[j] = bf16_rne(src[j * K2]);
        *(uint4*)&wt[(size_t)s * 8] = *(uint4*)tmp;
    }
}

__global__ __launch_bounds__(256, 4)
void dcn_mfma4_kernel(const ushort* __restrict__ xt,
                      const ushort* __restrict__ wt,
                      const float* __restrict__ offset,
                      const float* __restrict__ mask,
                      const float* __restrict__ bias,
                      float* __restrict__ out)
{
    __shared__ ushort s_w[CO * CI];          // SINGLE tap slab, swizzled, 32KB

    const int tid  = threadIdx.x;
    const int bid  = blockIdx.x;
    const int n    = bid & 7;                // XCD swizzle (n per XCD)
    const int tile = bid >> 3;               // 0..143
    const int ty   = tile / 6;               // 0..23 -> y0 = ty*4
    const int tx   = tile - ty * 6;          // 0..5  -> x0 = tx*16
    const int wave = tid >> 6;
    const int lane = tid & 63;
    const int l15  = lane & 15;              // pixel within wave row
    const int quad = lane >> 4;              // k-chunk within cb

    // this lane's pixel (same for all 4 quads -> redundant meta, cheap)
    const int ph = ty * 4 + wave;
    const int pw = tx * 16 + l15;
    const int p  = ph * WI + pw;

    auto stage = [&](int k) {
        const ushort* g = wt + ((size_t)k * 2048 + wave * 512) * 8;
        ushort* l = &s_w[wave * 512 * 8];
        #pragma unroll
        for (int i = 0; i < 8; ++i)
            gll16(g + (size_t)(i * 64 + lane) * 8, l + i * 64 * 8);
    };

    // issue the 3 meta loads for tap k
    auto metaload = [&](int k, float& oy, float& ox, float& mm) {
        oy = offset[((size_t)n * (2 * K2) + 2 * k    ) * P_TOT + p];
        ox = offset[((size_t)n * (2 * K2) + 2 * k + 1) * P_TOT + p];
        mm = mask  [((size_t)n * K2 + k) * P_TOT + p];
    };

    // per-lane bilinear meta for tap k (branchless)
    auto metacalc = [&](int k, float oy, float ox, float mm,
                        int& i00, int& i01, int& i10, int& i11, float4& mw) {
        int ky = k / 3, kx = k - ky * 3;
        float py = (float)(ph - 1 + ky) + oy;
        float px = (float)(pw - 1 + kx) + ox;
        float y0f = floorf(py), x0f = floorf(px);
        float wy = py - y0f, wx = px - x0f;
        int y0 = (int)y0f, x0 = (int)x0f;
        int y1 = y0 + 1,  x1 = x0 + 1;
        bool vy0 = (y0 >= 0) && (y0 < HI);
        bool vy1 = (y1 >= 0) && (y1 < HI);
        bool vx0 = (x0 >= 0) && (x0 < WI);
        bool vx1 = (x1 >= 0) && (x1 < WI);
        i00 = (vy0 && vx0) ? (y0 * WI + x0) : 0;
        i01 = (vy0 && vx1) ? (y0 * WI + x1) : 0;
        i10 = (vy1 && vx0) ? (y1 * WI + x0) : 0;
        i11 = (vy1 && vx1) ? (y1 * WI + x1) : 0;
        mw.x = (vy0 && vx0) ? (1.f - wy) * (1.f - wx) * mm : 0.f;
        mw.y = (vy0 && vx1) ? (1.f - wy) * wx          * mm : 0.f;
        mw.z = (vy1 && vx0) ? wy * (1.f - wx)          * mm : 0.f;
        mw.w = (vy1 && vx1) ? wy * wx                  * mm : 0.f;
    };

    f32x4 acc[8];
    #pragma unroll
    for (int a = 0; a < 8; ++a) acc[a] = (f32x4){0.f, 0.f, 0.f, 0.f};

    // chunk-plane base for this lane: plane quad of n; cb adds 4 planes
    const ushort* xp = xt + ((size_t)n * 16 + quad) * PLANE;

    uint4 g0[4], g1[4], g2[4], g3[4];
    float4 mwc;

    // 16 gathers: lane reads 16B (8 ch of plane cb*4+quad) at its pixel's
    // corner row -> B-frag layout directly (col=l15, k=quad*8+j)
    auto fetch = [&](int i00, int i01, int i10, int i11) {
        size_t r00 = (size_t)i00 * 8, r01 = (size_t)i01 * 8;
        size_t r10 = (size_t)i10 * 8, r11 = (size_t)i11 * 8;
        #pragma unroll
        for (int cb = 0; cb < 4; ++cb) {
            const ushort* pb = xp + (size_t)cb * 4 * PLANE;
            g0[cb] = *(const uint4*)(pb + r00);
            g1[cb] = *(const uint4*)(pb + r01);
            g2[cb] = *(const uint4*)(pb + r10);
            g3[cb] = *(const uint4*)(pb + r11);
        }
    };

    auto compute = [&]() {
        float2 w0 = make_float2(mwc.x, mwc.x);
        float2 w1 = make_float2(mwc.y, mwc.y);
        float2 w2 = make_float2(mwc.z, mwc.z);
        float2 w3 = make_float2(mwc.w, mwc.w);
        #pragma unroll
        for (int cb = 0; cb < 4; ++cb) {
            uint4 r0 = g0[cb], r1 = g1[cb], r2 = g2[cb], r3 = g3[cb];
            U4S8 cvt;
            {
                float2 pq = pk_mul(w0, unpk(r0.x));
                pq = pk_fma(w1, unpk(r1.x), pq);
                pq = pk_fma(w2, unpk(r2.x), pq);
                pq = pk_fma(w3, unpk(r3.x), pq);
                cvt.u.x = cvt_pk_bf16(pq.x, pq.y);
            }
            {
                float2 pq = pk_mul(w0, unpk(r0.y));
                pq = pk_fma(w1, unpk(r1.y), pq);
                pq = pk_fma(w2, unpk(r2.y), pq);
                pq = pk_fma(w3, unpk(r3.y), pq);
                cvt.u.y = cvt_pk_bf16(pq.x, pq.y);
            }
            {
                float2 pq = pk_mul(w0, unpk(r0.z));
                pq = pk_fma(w1, unpk(r1.z), pq);
                pq = pk_fma(w2, unpk(r2.z), pq);
                pq = pk_fma(w3, unpk(r3.z), pq);
                cvt.u.z = cvt_pk_bf16(pq.x, pq.y);
            }
            {
                float2 pq = pk_mul(w0, unpk(r0.w));
                pq = pk_fma(w1, unpk(r1.w), pq);
                pq = pk_fma(w2, unpk(r2.w), pq);
                pq = pk_fma(w3, unpk(r3.w), pq);
                cvt.u.w = cvt_pk_bf16(pq.x, pq.y);
            }
            short8 bfr = cvt.s;
            // afr slot is ot-invariant: slot = (cb*4+quad)^l15 -> 8 reads
            // from one base + immediate offsets (ot*4096B)
            const ushort* wbase = &s_w[l15 * CI + (((cb * 4 + quad) ^ l15) * 8)];
            __builtin_amdgcn_s_setprio(1);
            #pragma unroll
            for (int ot = 0; ot < 8; ++ot) {
                short8 afr = *(const short8*)(wbase + ot * 16 * CI);
                acc[ot] = __builtin_amdgcn_mfma_f32_16x16x32_bf16(afr, bfr, acc[ot], 0, 0, 0);
            }
            __builtin_amdgcn_s_setprio(0);
        }
    };

    // ---- prologue ----
    stage(0);                                // 8 DMAs in flight
    __builtin_amdgcn_sched_barrier(0);
    float oyc, oxc, mmc;
    metaload(0, oyc, oxc, mmc);              // consume below drains stage(0)
    int i00, i01, i10, i11;
    metacalc(0, oyc, oxc, mmc, i00, i01, i10, i11, mwc);
    fetch(i00, i01, i10, i11);               // tap-0 gathers in flight
    float oy1, ox1, mm1;
    metaload(1, oy1, ox1, mm1);
    __builtin_amdgcn_s_barrier();            // slab0 landed (drained above)

    for (int k = 0; k < 8; ++k) {
        compute();                           // slab k + gathers k
        float4 nmw;
        metacalc(k + 1, oy1, ox1, mm1, i00, i01, i10, i11, nmw);
        __builtin_amdgcn_s_barrier();        // all waves done reading slab k
        stage(k + 1);                        // 8 DMAs (oldest new VMEM)
        __builtin_amdgcn_sched_barrier(0);
        fetch(i00, i01, i10, i11);           // 16 gathers
        mwc = nmw;
        __builtin_amdgcn_sched_barrier(0);
        int k2 = (k + 2 > 8) ? 8 : k + 2;
        metaload(k2, oy1, ox1, mm1);         // 3 loads (newest)
        __builtin_amdgcn_sched_barrier(0);
        asm volatile("s_waitcnt vmcnt(19)" ::: "memory");  // DMAs landed
        __builtin_amdgcn_sched_barrier(0);
        __builtin_amdgcn_s_barrier();        // every wave's DMA landed
    }
    compute();                               // tap 8

    // ---- epilogue (wave = iy row of the 4x16 tile, l15 = ix) ----
    const int pbase = p;
    #pragma unroll
    for (int ot = 0; ot < 8; ++ot) {
        #pragma unroll
        for (int r = 0; r < 4; ++r) {
            int o = ot * 16 + quad * 4 + r;
            out[((size_t)n * CO + o) * P_TOT + pbase] = acc[ot][r] + bias[o];
        }
    }
}

// ---------------- fallback (no workspace): round-2 structure ----------------
__global__ __launch_bounds__(256, 3)
void dcn_fallback_kernel(const float* __restrict__ x,
                         const float* __restrict__ offset,
                         const float* __restrict__ mask,
                         const float* __restrict__ weight,
                         const float* __restrict__ bias,
                         float* __restrict__ out)
{
    __shared__ uint2  s_midx[K2 * TP];
    __shared__ float4 s_mw[K2 * TP];
    __shared__ ushort s_v[TP * CPAD];
    __shared__ ushort s_w[CO * CPAD];

    const int tid  = threadIdx.x;
    const int bid  = blockIdx.x;
    const int n    = bid & 7;
    const int p0   = (bid >> 3) * TP;

    for (int it = 0; it < 3; ++it) {
        int item = it * 256 + tid;
        if (item < K2 * TP) {
            int k = item / TP;
            int i = item % TP;
            int p  = p0 + i;
            int ph = p / WI;
            int pw = p % WI;
            float offy = offset[((size_t)n * (2 * K2) + 2 * k    ) * P_TOT + p];
            float offx = offset[((size_t)n * (2 * K2) + 2 * k + 1) * P_TOT + p];
            float m    = mask  [((size_t)n * K2 + k) * P_TOT + p];
            int ky = k / 3, kx = k % 3;
            float py = (float)(ph - 1 + ky) + offy;
            float px = (float)(pw - 1 + kx) + offx;
            float y0f = floorf(py), x0f = floorf(px);
            float wy = py - y0f, wx = px - x0f;
            int y0 = (int)y0f, x0 = (int)x0f;
            int y1 = y0 + 1,  x1 = x0 + 1;
            bool vy0 = (y0 >= 0) && (y0 < HI);
            bool vy1 = (y1 >= 0) && (y1 < HI);
            bool vx0 = (x0 >= 0) && (x0 < WI);
            bool vx1 = (x1 >= 0) && (x1 < WI);
            unsigned i00 = (vy0 && vx0) ? (unsigned)(y0 * WI + x0) : 0u;
            unsigned i01 = (vy0 && vx1) ? (unsigned)(y0 * WI + x1) : 0u;
            unsigned i10 = (vy1 && vx0) ? (unsigned)(y1 * WI + x0) : 0u;
            unsigned i11 = (vy1 && vx1) ? (unsigned)(y1 * WI + x1) : 0u;
            float w00 = (vy0 && vx0) ? (1.f - wy) * (1.f - wx) * m : 0.f;
            float w01 = (vy0 && vx1) ? (1.f - wy) * wx          * m : 0.f;
            float w10 = (vy1 && vx0) ? wy * (1.f - wx)          * m : 0.f;
            float w11 = (vy1 && vx1) ? wy * wx                  * m : 0.f;
            s_midx[item] = make_uint2(i00 | (i01 << 16), i10 | (i11 << 16));
            s_mw[item]   = make_float4(w00, w01, w10, w11);
        }
    }
    __syncthreads();

    const int wave = tid >> 6;
    const int lane = tid & 63;
    const int l15  = lane & 15;
    const int quad = lane >> 4;
    const int o_base = (wave >> 1) * 64;
    const int p_base = (wave & 1) * 32;
    const int gp = tid & 63;
    const int cg = wave;

    f32x4 acc[4][2];
    #pragma unroll
    for (int a = 0; a < 4; ++a)
        #pragma unroll
        for (int b = 0; b < 2; ++b) acc[a][b] = (f32x4){0.f, 0.f, 0.f, 0.f};

    for (int cb = 0; cb < 4; ++cb) {
        for (int k = 0; k < K2; ++k) {
            {
                uint2  mi = s_midx[k * TP + gp];
                float4 mw = s_mw[k * TP + gp];
                int i00 = mi.x & 0xFFFF, i01 = mi.x >> 16;
                int i10 = mi.y & 0xFFFF, i11 = mi.y >> 16;
                const float* xb = x + ((size_t)(n * CI + cb * 32 + cg * 8)) * (HI * WI);
                float v[8];
                #pragma unroll
                for (int j = 0; j < 8; ++j) {
                    const float* xp = xb + (size_t)j * (HI * WI);
                    v[j] = mw.x * xp[i00] + mw.y * xp[i01]
                         + mw.z * xp[i10] + mw.w * xp[i11];
                }
                uint4 pk;
                pk.x = pack_bf2(v[0], v[1]);
                pk.y = pack_bf2(v[2], v[3]);
                pk.z = pack_bf2(v[4], v[5]);
                pk.w = pack_bf2(v[6], v[7]);
                *(uint4*)&s_v[gp * CPAD + cg * 8] = pk;
            }
            {
                int o = tid >> 1, half = tid & 1;
                const float* wsrc = weight + (size_t)o * (CI * K2)
                                  + (cb * 32 + half * 16) * K2 + k;
                ushort tmp[16];
                #pragma unroll
                for (int i = 0; i < 16; ++i) tmp[i] = bf16_rne(wsrc[i * K2]);
                *(uint4*)&s_w[o * CPAD + half * 16]     = *(uint4*)&tmp[0];
                *(uint4*)&s_w[o * CPAD + half * 16 + 8] = *(uint4*)&tmp[8];
            }
            __syncthreads();
            short8 afr[4], bfr[2];
            #pragma unroll
            for (int ot = 0; ot < 4; ++ot)
                afr[ot] = *(const short8*)&s_w[(o_base + ot * 16 + l15) * CPAD + quad * 8];
            #pragma unroll
            for (int pt = 0; pt < 2; ++pt)
                bfr[pt] = *(const short8*)&s_v[(p_base + pt * 16 + l15) * CPAD + quad * 8];
            #pragma unroll
            for (int ot = 0; ot < 4; ++ot)
                #pragma unroll
                for (int pt = 0; pt < 2; ++pt)
                    acc[ot][pt] = __builtin_amdgcn_mfma_f32_16x16x32_bf16(
                        afr[ot], bfr[pt], acc[ot][pt], 0, 0, 0);
            __syncthreads();
        }
    }

    #pragma unroll
    for (int ot = 0; ot < 4; ++ot)
        #pragma unroll
        for (int r = 0; r < 4; ++r) {
            int o = o_base + ot * 16 + quad * 4 + r;
            float b = bias[o];
            #pragma unroll
            for (int pt = 0; pt < 2; ++pt) {
                int p = p0 + p_base + pt * 16 + l15;
                out[((size_t)n * CO + o) * P_TOT + p] = acc[ot][pt][r] + b;
            }
        }
}

extern "C" void kernel_launch(void* const* d_in, const int* in_sizes, int n_in,
                              void* d_out, int out_size, void* d_ws, size_t ws_size,
                              hipStream_t stream) {
    const float* x      = (const float*)d_in[0];
    const float* offset = (const float*)d_in[1];
    const float* mask   = (const float*)d_in[2];
    const float* weight = (const float*)d_in[3];
    const float* bias   = (const float*)d_in[4];
    float* out = (float*)d_out;

    dim3 block(256);
    if (ws_size >= WS_NEED) {
        ushort* xt = (ushort*)d_ws;
        ushort* wt = xt + XT_ELEMS;
        pre_kernel<<<dim3(2304 + 72), block, 0, stream>>>(x, weight, xt, wt);
        dcn_mfma4_kernel<<<dim3(NI * NTILE), block, 0, stream>>>(
            xt, wt, offset, mask, bias, out);
    } else {
        dcn_fallback_kernel<<<dim3(NI * NTILE), block, 0, stream>>>(
            x, offset, mask, weight, bias, out);
    }
}

// Round 14
// 160.857 us; speedup vs baseline: 1.0996x; 1.0996x over previous
//
#include <hip/hip_runtime.h>

// DCNv2 fused v16 = v14 + 4-bit XOR weight swizzle ONLY (v15 decomposed).
// v15 counters: bank conflicts 5.3M->0 (swizzle WORKS) but FETCH +6.6MB /
// WRITE +9.4MB = scratch spills from v_pk_fma_f32 inline-asm (float2 "v"
// operands need even-aligned VGPR pairs; allocator spilled around 16 live
// uint4 gathers) -> 78.5->90us. v16 keeps the swizzle (slot = csw^(o&15),
// read slot (cb*4+quad)^l15, ot-invariant base + immediate offsets) and
// reverts bilinear to v14's scalar FMA form (compiler regalloc-friendly).
// Clean A/B vs v14: conflicts 5.3M vs 0, same math path.

#define NI 8
#define CI 128
#define HI 96
#define WI 96
#define CO 128
#define K2 9
#define P_TOT 9216
#define TP 64
#define NTILE 144                                   // 24 ty * 6 tx
#define CPAD 40
#define XT_ELEMS ((size_t)NI * P_TOT * CI)          // 9,437,184 bf16
#define WT_ELEMS ((size_t)K2 * CO * CI)             // 147,456 bf16
#define WS_NEED ((XT_ELEMS + WT_ELEMS) * 2)
#define PLANE ((size_t)P_TOT * 8)                   // ushorts per chunk-plane

typedef short short8 __attribute__((ext_vector_type(8)));
typedef float f32x4 __attribute__((ext_vector_type(4)));

static __device__ __forceinline__ ushort bf16_rne(float x) {
    unsigned u = __float_as_uint(x);
    u = (u + 0x7FFF + ((u >> 16) & 1)) >> 16;
    return (ushort)u;
}
static __device__ __forceinline__ unsigned pack_bf2(float a, float b) {
    return (unsigned)bf16_rne(a) | ((unsigned)bf16_rne(b) << 16);
}
static __device__ __forceinline__ unsigned cvt_pk_bf16(float a, float b) {
    unsigned r;
    asm("v_cvt_pk_bf16_f32 %0, %1, %2" : "=v"(r) : "v"(a), "v"(b));
    return r;
}
static __device__ __forceinline__ float bflo(unsigned u) { return __uint_as_float(u << 16); }
static __device__ __forceinline__ float bfhi(unsigned u) { return __uint_as_float(u & 0xFFFF0000u); }

union U4S8 { uint4 u; short8 s; };

// async global->LDS, 16B per lane; LDS dest = wave-uniform base + lane*16
static __device__ __forceinline__ void gll16(const ushort* g, ushort* l) {
    __builtin_amdgcn_global_load_lds(
        (const __attribute__((address_space(1))) unsigned int*)g,
        (__attribute__((address_space(3))) unsigned int*)l, 16, 0, 0);
}

// ---- pre-kernel: grid = 2304 (x transpose) + 72 (weight recast+swizzle) ----
__global__ __launch_bounds__(256)
void pre_kernel(const float* __restrict__ x, const float* __restrict__ w,
                ushort* __restrict__ xt, ushort* __restrict__ wt) {
    const int bid = blockIdx.x;
    const int tid = threadIdx.x;
    if (bid < 2304) {
        // transpose x[n][c][hw] fp32 -> xt[n][chunk(16)][hw][8ch] bf16
        __shared__ ushort t[64][68];
        const int n = bid / 288, rr = bid % 288;
        const int cblk = rr & 1, hw0 = (rr >> 1) * 64;
        #pragma unroll
        for (int j = 0; j < 4; ++j) {
            int item = j * 256 + tid;               // < 1024
            int c = item >> 4, q = item & 15;
            float4 f = *(const float4*)(x + ((size_t)(n * CI + cblk * 64 + c)) * P_TOT
                                        + hw0 + q * 4);
            t[q * 4 + 0][c] = bf16_rne(f.x);
            t[q * 4 + 1][c] = bf16_rne(f.y);
            t[q * 4 + 2][c] = bf16_rne(f.z);
            t[q * 4 + 3][c] = bf16_rne(f.w);
        }
        __syncthreads();
        #pragma unroll
        for (int j = 0; j < 4; ++j) {
            int item = j * 256 + tid;               // < 1024
            int row = item >> 4, seg = item & 15;   // seg = 4-ch group
            uint2 v = *(const uint2*)&t[row][seg * 4];
            int chunk = cblk * 8 + (seg >> 1);      // 8-ch plane index
            int sub   = (seg & 1) * 4;
            *(uint2*)(xt + ((size_t)n * 16 + chunk) * PLANE
                         + (size_t)(hw0 + row) * 8 + sub) = v;
        }
    } else {
        // wt swizzled for LDS (4-bit XOR): slot s = k*2048 + o*16 + csw
        // holds 8 ch of c-seg cs = csw ^ (o&15); DMA's linear fill gives
        // the swizzled layout. Read side: slot = cs ^ (o&15).
        int s = (bid - 2304) * 256 + tid;           // < 18432
        int k   = s >> 11;
        int r2  = s & 2047;
        int o   = r2 >> 4;
        int csw = r2 & 15;
        int cs  = csw ^ (o & 15);
        const float* src = w + (size_t)o * (CI * K2) + cs * 8 * K2 + k;
        ushort tmp[8];
        #pragma unroll
        for (int j = 0; j < 8; ++j) tmp[j] = bf16_rne(src[j * K2]);
        *(uint4*)&wt[(size_t)s * 8] = *(uint4*)tmp;
    }
}

__global__ __launch_bounds__(256, 4)
void dcn_mfma4_kernel(const ushort* __restrict__ xt,
                      const ushort* __restrict__ wt,
                      const float* __restrict__ offset,
                      const float* __restrict__ mask,
                      const float* __restrict__ bias,
                      float* __restrict__ out)
{
    __shared__ ushort s_w[CO * CI];          // SINGLE tap slab, swizzled, 32KB

    const int tid  = threadIdx.x;
    const int bid  = blockIdx.x;
    const int n    = bid & 7;                // XCD swizzle (n per XCD)
    const int tile = bid >> 3;               // 0..143
    const int ty   = tile / 6;               // 0..23 -> y0 = ty*4
    const int tx   = tile - ty * 6;          // 0..5  -> x0 = tx*16
    const int wave = tid >> 6;
    const int lane = tid & 63;
    const int l15  = lane & 15;              // pixel within wave row
    const int quad = lane >> 4;              // k-chunk within cb

    // this lane's pixel (same for all 4 quads -> redundant meta, cheap)
    const int ph = ty * 4 + wave;
    const int pw = tx * 16 + l15;
    const int p  = ph * WI + pw;

    auto stage = [&](int k) {
        const ushort* g = wt + ((size_t)k * 2048 + wave * 512) * 8;
        ushort* l = &s_w[wave * 512 * 8];
        #pragma unroll
        for (int i = 0; i < 8; ++i)
            gll16(g + (size_t)(i * 64 + lane) * 8, l + i * 64 * 8);
    };

    // issue the 3 meta loads for tap k
    auto metaload = [&](int k, float& oy, float& ox, float& mm) {
        oy = offset[((size_t)n * (2 * K2) + 2 * k    ) * P_TOT + p];
        ox = offset[((size_t)n * (2 * K2) + 2 * k + 1) * P_TOT + p];
        mm = mask  [((size_t)n * K2 + k) * P_TOT + p];
    };

    // per-lane bilinear meta for tap k (branchless)
    auto metacalc = [&](int k, float oy, float ox, float mm,
                        int& i00, int& i01, int& i10, int& i11, float4& mw) {
        int ky = k / 3, kx = k - ky * 3;
        float py = (float)(ph - 1 + ky) + oy;
        float px = (float)(pw - 1 + kx) + ox;
        float y0f = floorf(py), x0f = floorf(px);
        float wy = py - y0f, wx = px - x0f;
        int y0 = (int)y0f, x0 = (int)x0f;
        int y1 = y0 + 1,  x1 = x0 + 1;
        bool vy0 = (y0 >= 0) && (y0 < HI);
        bool vy1 = (y1 >= 0) && (y1 < HI);
        bool vx0 = (x0 >= 0) && (x0 < WI);
        bool vx1 = (x1 >= 0) && (x1 < WI);
        i00 = (vy0 && vx0) ? (y0 * WI + x0) : 0;
        i01 = (vy0 && vx1) ? (y0 * WI + x1) : 0;
        i10 = (vy1 && vx0) ? (y1 * WI + x0) : 0;
        i11 = (vy1 && vx1) ? (y1 * WI + x1) : 0;
        mw.x = (vy0 && vx0) ? (1.f - wy) * (1.f - wx) * mm : 0.f;
        mw.y = (vy0 && vx1) ? (1.f - wy) * wx          * mm : 0.f;
        mw.z = (vy1 && vx0) ? wy * (1.f - wx)          * mm : 0.f;
        mw.w = (vy1 && vx1) ? wy * wx                  * mm : 0.f;
    };

    f32x4 acc[8];
    #pragma unroll
    for (int a = 0; a < 8; ++a) acc[a] = (f32x4){0.f, 0.f, 0.f, 0.f};

    // chunk-plane base for this lane: plane quad of n; cb adds 4 planes
    const ushort* xp = xt + ((size_t)n * 16 + quad) * PLANE;

    uint4 g0[4], g1[4], g2[4], g3[4];
    float4 mwc;

    // 16 gathers: lane reads 16B (8 ch of plane cb*4+quad) at its pixel's
    // corner row -> B-frag layout directly (col=l15, k=quad*8+j)
    auto fetch = [&](int i00, int i01, int i10, int i11) {
        size_t r00 = (size_t)i00 * 8, r01 = (size_t)i01 * 8;
        size_t r10 = (size_t)i10 * 8, r11 = (size_t)i11 * 8;
        #pragma unroll
        for (int cb = 0; cb < 4; ++cb) {
            const ushort* pb = xp + (size_t)cb * 4 * PLANE;
            g0[cb] = *(const uint4*)(pb + r00);
            g1[cb] = *(const uint4*)(pb + r01);
            g2[cb] = *(const uint4*)(pb + r10);
            g3[cb] = *(const uint4*)(pb + r11);
        }
    };

    auto compute = [&]() {
        #pragma unroll
        for (int cb = 0; cb < 4; ++cb) {
            uint4 r0 = g0[cb], r1 = g1[cb], r2 = g2[cb], r3 = g3[cb];
            float v0 = mwc.x * bflo(r0.x) + mwc.y * bflo(r1.x) + mwc.z * bflo(r2.x) + mwc.w * bflo(r3.x);
            float v1 = mwc.x * bfhi(r0.x) + mwc.y * bfhi(r1.x) + mwc.z * bfhi(r2.x) + mwc.w * bfhi(r3.x);
            float v2 = mwc.x * bflo(r0.y) + mwc.y * bflo(r1.y) + mwc.z * bflo(r2.y) + mwc.w * bflo(r3.y);
            float v3 = mwc.x * bfhi(r0.y) + mwc.y * bfhi(r1.y) + mwc.z * bfhi(r2.y) + mwc.w * bfhi(r3.y);
            float v4 = mwc.x * bflo(r0.z) + mwc.y * bflo(r1.z) + mwc.z * bflo(r2.z) + mwc.w * bflo(r3.z);
            float v5 = mwc.x * bfhi(r0.z) + mwc.y * bfhi(r1.z) + mwc.z * bfhi(r2.z) + mwc.w * bfhi(r3.z);
            float v6 = mwc.x * bflo(r0.w) + mwc.y * bflo(r1.w) + mwc.z * bflo(r2.w) + mwc.w * bflo(r3.w);
            float v7 = mwc.x * bfhi(r0.w) + mwc.y * bfhi(r1.w) + mwc.z * bfhi(r2.w) + mwc.w * bfhi(r3.w);
            U4S8 cvt;
            cvt.u.x = cvt_pk_bf16(v0, v1);   // already MFMA B-frag layout
            cvt.u.y = cvt_pk_bf16(v2, v3);
            cvt.u.z = cvt_pk_bf16(v4, v5);
            cvt.u.w = cvt_pk_bf16(v6, v7);
            short8 bfr = cvt.s;
            // afr slot is ot-invariant: slot = (cb*4+quad)^l15 -> 8 reads
            // from one base + immediate offsets (ot*4096B); conflict-free
            const ushort* wbase = &s_w[l15 * CI + (((cb * 4 + quad) ^ l15) * 8)];
            __builtin_amdgcn_s_setprio(1);
            #pragma unroll
            for (int ot = 0; ot < 8; ++ot) {
                short8 afr = *(const short8*)(wbase + ot * 16 * CI);
                acc[ot] = __builtin_amdgcn_mfma_f32_16x16x32_bf16(afr, bfr, acc[ot], 0, 0, 0);
            }
            __builtin_amdgcn_s_setprio(0);
        }
    };

    // ---- prologue ----
    stage(0);                                // 8 DMAs in flight
    __builtin_amdgcn_sched_barrier(0);
    float oyc, oxc, mmc;
    metaload(0, oyc, oxc, mmc);              // consume below drains stage(0)
    int i00, i01, i10, i11;
    metacalc(0, oyc, oxc, mmc, i00, i01, i10, i11, mwc);
    fetch(i00, i01, i10, i11);               // tap-0 gathers in flight
    float oy1, ox1, mm1;
    metaload(1, oy1, ox1, mm1);
    __builtin_amdgcn_s_barrier();            // slab0 landed (drained above)

    for (int k = 0; k < 8; ++k) {
        compute();                           // slab k + gathers k
        float4 nmw;
        metacalc(k + 1, oy1, ox1, mm1, i00, i01, i10, i11, nmw);
        __builtin_amdgcn_s_barrier();        // all waves done reading slab k
        stage(k + 1);                        // 8 DMAs (oldest new VMEM)
        __builtin_amdgcn_sched_barrier(0);
        fetch(i00, i01, i10, i11);           // 16 gathers
        mwc = nmw;
        __builtin_amdgcn_sched_barrier(0);
        int k2 = (k + 2 > 8) ? 8 : k + 2;
        metaload(k2, oy1, ox1, mm1);         // 3 loads (newest)
        __builtin_amdgcn_sched_barrier(0);
        asm volatile("s_waitcnt vmcnt(19)" ::: "memory");  // DMAs landed
        __builtin_amdgcn_sched_barrier(0);
        __builtin_amdgcn_s_barrier();        // every wave's DMA landed
    }
    compute();                               // tap 8

    // ---- epilogue (wave = iy row of the 4x16 tile, l15 = ix) ----
    const int pbase = p;
    #pragma unroll
    for (int ot = 0; ot < 8; ++ot) {
        #pragma unroll
        for (int r = 0; r < 4; ++r) {
            int o = ot * 16 + quad * 4 + r;
            out[((size_t)n * CO + o) * P_TOT + pbase] = acc[ot][r] + bias[o];
        }
    }
}

// ---------------- fallback (no workspace): round-2 structure ----------------
__global__ __launch_bounds__(256, 3)
void dcn_fallback_kernel(const float* __restrict__ x,
                         const float* __restrict__ offset,
                         const float* __restrict__ mask,
                         const float* __restrict__ weight,
                         const float* __restrict__ bias,
                         float* __restrict__ out)
{
    __shared__ uint2  s_midx[K2 * TP];
    __shared__ float4 s_mw[K2 * TP];
    __shared__ ushort s_v[TP * CPAD];
    __shared__ ushort s_w[CO * CPAD];

    const int tid  = threadIdx.x;
    const int bid  = blockIdx.x;
    const int n    = bid & 7;
    const int p0   = (bid >> 3) * TP;

    for (int it = 0; it < 3; ++it) {
        int item = it * 256 + tid;
        if (item < K2 * TP) {
            int k = item / TP;
            int i = item % TP;
            int p  = p0 + i;
            int ph = p / WI;
            int pw = p % WI;
            float offy = offset[((size_t)n * (2 * K2) + 2 * k    ) * P_TOT + p];
            float offx = offset[((size_t)n * (2 * K2) + 2 * k + 1) * P_TOT + p];
            float m    = mask  [((size_t)n * K2 + k) * P_TOT + p];
            int ky = k / 3, kx = k % 3;
            float py = (float)(ph - 1 + ky) + offy;
            float px = (float)(pw - 1 + kx) + offx;
            float y0f = floorf(py), x0f = floorf(px);
            float wy = py - y0f, wx = px - x0f;
            int y0 = (int)y0f, x0 = (int)x0f;
            int y1 = y0 + 1,  x1 = x0 + 1;
            bool vy0 = (y0 >= 0) && (y0 < HI);
            bool vy1 = (y1 >= 0) && (y1 < HI);
            bool vx0 = (x0 >= 0) && (x0 < WI);
            bool vx1 = (x1 >= 0) && (x1 < WI);
            unsigned i00 = (vy0 && vx0) ? (unsigned)(y0 * WI + x0) : 0u;
            unsigned i01 = (vy0 && vx1) ? (unsigned)(y0 * WI + x1) : 0u;
            unsigned i10 = (vy1 && vx0) ? (unsigned)(y1 * WI + x0) : 0u;
            unsigned i11 = (vy1 && vx1) ? (unsigned)(y1 * WI + x1) : 0u;
            float w00 = (vy0 && vx0) ? (1.f - wy) * (1.f - wx) * m : 0.f;
            float w01 = (vy0 && vx1) ? (1.f - wy) * wx          * m : 0.f;
            float w10 = (vy1 && vx0) ? wy * (1.f - wx)          * m : 0.f;
            float w11 = (vy1 && vx1) ? wy * wx                  * m : 0.f;
            s_midx[item] = make_uint2(i00 | (i01 << 16), i10 | (i11 << 16));
            s_mw[item]   = make_float4(w00, w01, w10, w11);
        }
    }
    __syncthreads();

    const int wave = tid >> 6;
    const int lane = tid & 63;
    const int l15  = lane & 15;
    const int quad = lane >> 4;
    const int o_base = (wave >> 1) * 64;
    const int p_base = (wave & 1) * 32;
    const int gp = tid & 63;
    const int cg = wave;

    f32x4 acc[4][2];
    #pragma unroll
    for (int a = 0; a < 4; ++a)
        #pragma unroll
        for (int b = 0; b < 2; ++b) acc[a][b] = (f32x4){0.f, 0.f, 0.f, 0.f};

    for (int cb = 0; cb < 4; ++cb) {
        for (int k = 0; k < K2; ++k) {
            {
                uint2  mi = s_midx[k * TP + gp];
                float4 mw = s_mw[k * TP + gp];
                int i00 = mi.x & 0xFFFF, i01 = mi.x >> 16;
                int i10 = mi.y & 0xFFFF, i11 = mi.y >> 16;
                const float* xb = x + ((size_t)(n * CI + cb * 32 + cg * 8)) * (HI * WI);
                float v[8];
                #pragma unroll
                for (int j = 0; j < 8; ++j) {
                    const float* xp = xb + (size_t)j * (HI * WI);
                    v[j] = mw.x * xp[i00] + mw.y * xp[i01]
                         + mw.z * xp[i10] + mw.w * xp[i11];
                }
                uint4 pk;
                pk.x = pack_bf2(v[0], v[1]);
                pk.y = pack_bf2(v[2], v[3]);
                pk.z = pack_bf2(v[4], v[5]);
                pk.w = pack_bf2(v[6], v[7]);
                *(uint4*)&s_v[gp * CPAD + cg * 8] = pk;
            }
            {
                int o = tid >> 1, half = tid & 1;
                const float* wsrc = weight + (size_t)o * (CI * K2)
                                  + (cb * 32 + half * 16) * K2 + k;
                ushort tmp[16];
                #pragma unroll
                for (int i = 0; i < 16; ++i) tmp[i] = bf16_rne(wsrc[i * K2]);
                *(uint4*)&s_w[o * CPAD + half * 16]     = *(uint4*)&tmp[0];
                *(uint4*)&s_w[o * CPAD + half * 16 + 8] = *(uint4*)&tmp[8];
            }
            __syncthreads();
            short8 afr[4], bfr[2];
            #pragma unroll
            for (int ot = 0; ot < 4; ++ot)
                afr[ot] = *(const short8*)&s_w[(o_base + ot * 16 + l15) * CPAD + quad * 8];
            #pragma unroll
            for (int pt = 0; pt < 2; ++pt)
                bfr[pt] = *(const short8*)&s_v[(p_base + pt * 16 + l15) * CPAD + quad * 8];
            #pragma unroll
            for (int ot = 0; ot < 4; ++ot)
                #pragma unroll
                for (int pt = 0; pt < 2; ++pt)
                    acc[ot][pt] = __builtin_amdgcn_mfma_f32_16x16x32_bf16(
                        afr[ot], bfr[pt], acc[ot][pt], 0, 0, 0);
            __syncthreads();
        }
    }

    #pragma unroll
    for (int ot = 0; ot < 4; ++ot)
        #pragma unroll
        for (int r = 0; r < 4; ++r) {
            int o = o_base + ot * 16 + quad * 4 + r;
            float b = bias[o];
            #pragma unroll
            for (int pt = 0; pt < 2; ++pt) {
                int p = p0 + p_base + pt * 16 + l15;
                out[((size_t)n * CO + o) * P_TOT + p] = acc[ot][pt][r] + b;
            }
        }
}

extern "C" void kernel_launch(void* const* d_in, const int* in_sizes, int n_in,
                              void* d_out, int out_size, void* d_ws, size_t ws_size,
                              hipStream_t stream) {
    const float* x      = (const float*)d_in[0];
    const float* offset = (const float*)d_in[1];
    const float* mask   = (const float*)d_in[2];
    const float* weight = (const float*)d_in[3];
    const float* bias   = (const float*)d_in[4];
    float* out = (float*)d_out;

    dim3 block(256);
    if (ws_size >= WS_NEED) {
        ushort* xt = (ushort*)d_ws;
        ushort* wt = xt + XT_ELEMS;
        pre_kernel<<<dim3(2304 + 72), block, 0, stream>>>(x, weight, xt, wt);
        dcn_mfma4_kernel<<<dim3(NI * NTILE), block, 0, stream>>>(
            xt, wt, offset, mask, bias, out);
    } else {
        dcn_fallback_kernel<<<dim3(NI * NTILE), block, 0, stream>>>(
            x, offset, mask, weight, bias, out);
    }
}